// Round 10
// baseline (168.534 us; speedup 1.0000x reference)
//
#include <hip/hip_runtime.h>
#include <math.h>

#define H 28
#define N 784
#define B 32
#define T 25
#define NPAD 1024
#define MEDGE 1536
#define NOFF 3025   // 55*55 lattice offsets

// ---- numpy linspace replication (float64) ----
__device__ __forceinline__ double coord_r_f(int i) {
    if (i == H - 1) return 0.0;
    return 224.0 + (double)i * ((0.0 - 224.0) / 27.0);
}
__device__ __forceinline__ double coord_c_f(int j) {
    if (j == H - 1) return 224.0;
    return (double)j * (224.0 / 27.0);
}

__device__ __forceinline__ int pf_find(volatile float2* pf, int x, unsigned& fbits) {
    float2 e;
    e.x = pf[x].x; e.y = pf[x].y;
    int p = __float_as_int(e.y);
    while (p != x) {
        float2 ep;
        ep.x = pf[p].x; ep.y = pf[p].y;
        int gp = __float_as_int(ep.y);
        if (gp != p) { pf[x].x = ep.x; pf[x].y = ep.y; }   // path halving
        x = p; e = ep; p = gp;
    }
    fbits = __float_as_uint(e.x);
    return x;
}

// ============================================================
// K1 (everything but the head): one 1024-thread block per (m0,b).
// offset-table build -> DTM walk -> argsort -> basins -> UF -> landscapes
// ============================================================
__global__ __launch_bounds__(1024) void dtm_topo_kernel(
        const float* __restrict__ x, float* __restrict__ feat) {
    __shared__ double crtab[H], cctab[H];
    __shared__ unsigned short offs[NOFF];       // packed (dr+27)<<6 | (dc+27)
    __shared__ float lw[N];
    __shared__ unsigned long long skey64[NPAD]; // unioned: binbase / red
    __shared__ short rank_[N];
    __shared__ float2 pf_s[N];
    __shared__ short pd[N];
    __shared__ short labA[N];
    __shared__ short labB[N];
    __shared__ unsigned ev[MEDGE];
    __shared__ float fv[N];
    __shared__ float dv[N];
    __shared__ int wsum[32];
    volatile float2* pf = pf_s;
    int* binbase = (int*)skey64;     // table-build phase only
    float* red   = (float*)skey64;   // sum phase only

    const int prob = blockIdx.x;     // mi*32 + b
    const int b  = prob & 31;
    const int mi = prob >> 5;
    const float m0 = mi ? 0.2f : 0.05f;
    const int tid = threadIdx.x;
    const int wid = tid >> 6, lane = tid & 63;

    // ---- coord tables ----
    if (tid < H) { crtab[tid] = coord_r_f(tid); cctab[tid] = coord_c_f(tid); }

    // ---- bin counts: d2 values 2*tid, 2*tid+1 ----
    {
        int d0 = 2 * tid, d1 = 2 * tid + 1;
        int a0 = 0, a1 = 0;
        for (int dr = -27; dr <= 27; ++dr) {
            int q = dr * dr;
            int r0 = d0 - q;
            if (d0 <= 1458 && r0 >= 0) {
                int s = (int)(sqrtf((float)r0) + 0.5f);
                if (s * s == r0 && s <= 27) a0 += s ? 2 : 1;
            }
            int r1 = d1 - q;
            if (d1 <= 1458 && r1 >= 0) {
                int s = (int)(sqrtf((float)r1) + 0.5f);
                if (s * s == r1 && s <= 27) a1 += s ? 2 : 1;
            }
        }
        // block exclusive scan of (a0+a1)
        int deg = a0 + a1;
        int inc = deg;
        #pragma unroll
        for (int off = 1; off < 64; off <<= 1) {
            int nv = __shfl_up(inc, off, 64);
            if (lane >= off) inc += nv;
        }
        if (lane == 63) wsum[wid] = inc;
        __syncthreads();
        if (wid == 0) {
            int wv = (lane < 16) ? wsum[lane] : 0;
            #pragma unroll
            for (int off = 1; off < 16; off <<= 1) {
                int nv = __shfl_up(wv, off, 64);
                if (lane >= off) wv += nv;
            }
            if (lane < 16) wsum[16 + lane] = wv;
        }
        __syncthreads();
        int base = (wid ? wsum[16 + wid - 1] : 0) + (inc - deg);
        binbase[d0] = base;
        binbase[d1] = base + a0;
    }
    __syncthreads();
    // ---- scatter offsets into exact (d2, dr, dc) order ----
    #pragma unroll
    for (int kk = 0; kk < 3; ++kk) {
        int p = tid + kk * 1024;
        if (p < NOFF) {
            int dr = p / 55 - 27, dc = p % 55 - 27;
            int d2 = dr * dr + dc * dc;
            int rk = 0;
            for (int drp = -27; drp < dr; ++drp) {
                int rem = d2 - drp * drp;
                if (rem >= 0) {
                    int s = (int)(sqrtf((float)rem) + 0.5f);
                    if (s * s == rem && s <= 27) rk += s ? 2 : 1;
                }
            }
            if (dc > 0) rk += 1;
            offs[binbase[d2] + rk] = (unsigned short)(((dr + 27) << 6) | (dc + 27));
        }
    }
    __syncthreads();

    // ---- weights + total mass (same reduction shape as prior rounds) ----
    {
        float s = 0.f;
        if (tid < N) { float v = x[b * N + tid]; lw[tid] = v; s = v; }
        red[tid] = s;
        __syncthreads();
        for (int off = 512; off > 0; off >>= 1) {
            if (tid < off) red[tid] += red[tid + off];
            __syncthreads();
        }
    }
    const float m0W = m0 * red[0];
    __syncthreads();

    // ---- DTM walk over constant offset list (all-LDS) ----
    if (tid < N) {
        const int ri = tid / H, ci = tid % H;
        const double rri = crtab[ri], cci = cctab[ci];
        float cum = 0.f, acc = 0.f;
        for (int k0 = 0; k0 < NOFF; k0 += 32) {
            for (int c = 0; c < 32; ++c) {
                int idx = k0 + c;
                if (idx < NOFF) {
                    unsigned o = offs[idx];
                    int rj = ri + (int)(o >> 6) - 27;
                    int cj = ci + (int)(o & 63u) - 27;
                    if ((unsigned)rj < (unsigned)H && (unsigned)cj < (unsigned)H) {
                        float w = lw[rj * H + cj];
                        double ddr = rri - crtab[rj];
                        double ddc = cci - cctab[cj];
                        float d2 = (float)(ddr * ddr + ddc * ddc);
                        float rem = m0W - cum;
                        float contrib = fminf(fmaxf(rem, 0.f), w);
                        acc += contrib * d2;
                        cum += w;
                    }
                }
            }
            if (__all(cum >= m0W)) break;
        }
        fv[tid] = sqrtf(fmaxf(acc / m0W, 1e-12f));
    }
    __syncthreads();

    // ---- argsort: u64 keys (fbits<<10 | idx), bitonic 1024 ----
    skey64[tid] = (tid < N)
        ? ((((unsigned long long)__float_as_uint(fv[tid])) << 10) | (unsigned long long)tid)
        : ~0ull;
    __syncthreads();
    for (int k = 2; k <= NPAD; k <<= 1) {
        for (int j = k >> 1; j > 0; j >>= 1) {
            int a = tid, b2 = a ^ j;
            if (b2 > a) {
                unsigned long long ka = skey64[a], kb = skey64[b2];
                if ((ka > kb) == ((a & k) == 0)) { skey64[a] = kb; skey64[b2] = ka; }
            }
            __syncthreads();
        }
    }
    // ---- rank / pf / pd init ----
    if (tid < N) {
        rank_[(int)(skey64[tid] & 1023ull)] = (short)tid;
        pf_s[tid] = make_float2(fv[tid], __int_as_float(tid));
        pd[tid] = (short)tid;
    }
    __syncthreads();
    // ---- descent pointers ----
    if (tid < N) {
        int v = tid;
        int row = v / H, col = v % H;
        int best = (int)rank_[v], bestn = v;
        if (row > 0)     { int n = v - H, rn = (int)rank_[n]; if (rn < best) { best = rn; bestn = n; } }
        if (row < H - 1) { int n = v + H, rn = (int)rank_[n]; if (rn < best) { best = rn; bestn = n; } }
        if (col > 0)     { int n = v - 1, rn = (int)rank_[n]; if (rn < best) { best = rn; bestn = n; } }
        if (col < H - 1) { int n = v + 1, rn = (int)rank_[n]; if (rn < best) { best = rn; bestn = n; } }
        labA[v] = (short)bestn;
    }
    __syncthreads();
    // ---- pointer jumping (10 rounds covers any path) ----
    {
        short* lsrc = labA;
        short* ldst = labB;
        for (int it = 0; it < 10; ++it) {
            if (tid < N) ldst[tid] = lsrc[(int)lsrc[tid]];
            __syncthreads();
            short* t = lsrc; lsrc = ldst; ldst = t;
        }
    }
    const short* lab = labA;   // 10 swaps -> result back in labA
    // ---- candidate saddle edges (basin-differing), exact ref order ----
    int deg = 0;
    int vq = -1, rowq = 0, colq = 0, lvq = 0;
    if (tid < N) {
        int r = tid;
        vq = (int)(skey64[r] & 1023ull);
        rowq = vq / H; colq = vq % H; lvq = (int)lab[vq];
        deg += (rowq > 0     && (int)rank_[vq - H] < r && (int)lab[vq - H] != lvq);
        deg += (rowq < H - 1 && (int)rank_[vq + H] < r && (int)lab[vq + H] != lvq);
        deg += (colq > 0     && (int)rank_[vq - 1] < r && (int)lab[vq - 1] != lvq);
        deg += (colq < H - 1 && (int)rank_[vq + 1] < r && (int)lab[vq + 1] != lvq);
    }
    // block exclusive scan of deg
    int mc;
    {
        int inc = deg;
        #pragma unroll
        for (int off = 1; off < 64; off <<= 1) {
            int nv = __shfl_up(inc, off, 64);
            if (lane >= off) inc += nv;
        }
        if (lane == 63) wsum[wid] = inc;
        __syncthreads();
        if (wid == 0) {
            int wv = (lane < 16) ? wsum[lane] : 0;
            #pragma unroll
            for (int off = 1; off < 16; off <<= 1) {
                int nv = __shfl_up(wv, off, 64);
                if (lane >= off) wv += nv;
            }
            if (lane < 16) wsum[16 + lane] = wv;
        }
        __syncthreads();
        int base = (wid ? wsum[16 + wid - 1] : 0) + (inc - deg);
        mc = wsum[31];
        if (tid < N && deg) {
            int r = tid, pos = base;
            int nbs[4] = { vq - H, vq + H, vq - 1, vq + 1 };
            bool val[4] = { rowq > 0, rowq < H - 1, colq > 0, colq < H - 1 };
            #pragma unroll
            for (int k4 = 0; k4 < 4; ++k4) {
                if (val[k4] && (int)rank_[nbs[k4]] < r && (int)lab[nbs[k4]] != lvq) {
                    ev[pos] = (unsigned)vq | ((unsigned)lvq << 10)
                            | ((unsigned)(int)lab[nbs[k4]] << 20);
                    pos++;
                }
            }
        }
    }
    __syncthreads();

    // ---- wave-0 tiny UF over candidates (ballot resolve) ----
    if (tid < 64) {
        const int nch = (mc + 63) >> 6;
        for (int c = 0; c < nch; ++c) {
            int idx = c * 64 + lane;
            unsigned e = (idx < mc) ? ev[idx] : 0u;
            const int uu = (int)(e & 1023u);
            const int bu = (int)((e >> 10) & 1023u);
            const int bw = (int)((e >> 20) & 1023u);
            unsigned fa, fb;
            int ra = pf_find(pf, bu, fa);
            int rb = pf_find(pf, bw, fb);
            int myL = -1, myW = 0; unsigned myWF = 0;
            unsigned long long mask = __ballot(ra != rb);
            while (mask) {
                int j = __builtin_ctzll(mask);
                mask &= mask - 1;
                int s_a = __builtin_amdgcn_readlane(ra, j);
                int s_b = __builtin_amdgcn_readlane(rb, j);
                if (s_a != s_b) {          // uniform
                    unsigned s_fa = (unsigned)__builtin_amdgcn_readlane((int)fa, j);
                    unsigned s_fb = (unsigned)__builtin_amdgcn_readlane((int)fb, j);
                    bool nw = (s_fb < s_fa) || (s_fb == s_fa && s_b < s_a);
                    int s_w = nw ? s_b : s_a;
                    int s_l = nw ? s_a : s_b;
                    unsigned s_wf = nw ? s_fb : s_fa;
                    bool me = (lane == j);
                    myL  = me ? s_l  : myL;
                    myW  = me ? s_w  : myW;
                    myWF = me ? s_wf : myWF;
                    bool ha = (ra == s_l);
                    ra = ha ? s_w : ra; fa = ha ? s_wf : fa;
                    bool hb = (rb == s_l);
                    rb = hb ? s_w : rb; fb = hb ? s_wf : fb;
                }
            }
            if (myL >= 0) {                // losers distinct -> race-free
                pd[myL] = (short)uu;
                pf[myL].x = __uint_as_float(myWF);
                pf[myL].y = __int_as_float(myW);
            }
            __builtin_amdgcn_sched_barrier(0);
        }
        if (lane == 0) {
            unsigned dummy;
            int vmax = (int)(skey64[N - 1] & 1023ull);   // last real sorted slot
            int g = pf_find(pf, (int)lab[vmax], dummy);
            pd[g] = (short)vmax;
        }
    }
    __syncthreads();

    // ---- death values (linearize the gather once) ----
    if (tid < N) dv[tid] = fv[(int)pd[tid]];
    __syncthreads();

    // ---- landscapes: top-2 per t, linear reads ----
    for (int t = wid; t < T; t += 16) {
        float tval = (t == T - 1) ? 80.0f : (1.0f + (float)t * (79.0f / 24.0f));
        float m1 = 0.f, m2 = 0.f;
        for (int i = lane; i < N; i += 64) {
            float tv = fminf(tval - fv[i], dv[i] - tval);
            tv = fmaxf(tv, 0.f);
            float lo = fminf(tv, m1);
            m1 = fmaxf(tv, m1);
            m2 = fmaxf(m2, lo);
        }
        #pragma unroll
        for (int off = 32; off > 0; off >>= 1) {
            float o1 = __shfl_down(m1, off, 64);
            float o2 = __shfl_down(m2, off, 64);
            float hi = fmaxf(m1, o1);
            float lo = fminf(m1, o1);
            m2 = fmaxf(fmaxf(m2, o2), lo);
            m1 = hi;
        }
        if (lane == 0) {
            feat[prob * 50 + t]     = m1;
            feat[prob * 50 + T + t] = m2;
        }
    }
}

// ============================================================
// K2: head.
// ============================================================
__global__ void head_kernel(const float* __restrict__ feat,
                            const float* __restrict__ wg1, const float* __restrict__ bg1,
                            const float* __restrict__ wg2, const float* __restrict__ bg2,
                            const float* __restrict__ fcw, const float* __restrict__ fcb,
                            float* __restrict__ out) {
    __shared__ float xc[B * 100];
    const int tid = threadIdx.x;
    for (int e = tid; e < B * 100; e += 256) {
        int b = e / 100, j = e % 100;
        const float* fp; const float* wrow; float bias;
        if (j < 50) { fp = feat + b * 50;       wrow = wg1 + j * 50;        bias = bg1[j]; }
        else        { fp = feat + (B + b) * 50; wrow = wg2 + (j - 50) * 50; bias = bg2[j - 50]; }
        float acc = bias;
        for (int q = 0; q < 50; ++q) acc += fp[q] * wrow[q];
        xc[e] = acc;
    }
    __syncthreads();
    for (int j = tid; j < 100; j += 256) {
        float s = 0.f;
        for (int b = 0; b < B; ++b) s += fabsf(xc[b * 100 + j]);
        out[320 + j] = s;
    }
    for (int e = tid; e < 320; e += 256) {
        int b = e / 10, o = e % 10;
        float acc = fcb[o];
        for (int j = 0; j < 100; ++j)
            acc += fmaxf(xc[b * 100 + j], 0.f) * fcw[o * 100 + j];
        out[e] = acc;
    }
}

extern "C" void kernel_launch(void* const* d_in, const int* in_sizes, int n_in,
                              void* d_out, int out_size, void* d_ws, size_t ws_size,
                              hipStream_t stream) {
    (void)in_sizes; (void)n_in; (void)out_size; (void)ws_size;
    const float* x   = (const float*)d_in[0];
    const float* wg1 = (const float*)d_in[1];
    const float* bg1 = (const float*)d_in[2];
    const float* wg2 = (const float*)d_in[3];
    const float* bg2 = (const float*)d_in[4];
    const float* fcw = (const float*)d_in[5];
    const float* fcb = (const float*)d_in[6];
    float* out = (float*)d_out;

    float* feat = (float*)d_ws;   // 64*50 f32

    dtm_topo_kernel<<<dim3(64), dim3(1024), 0, stream>>>(x, feat);
    head_kernel<<<dim3(1), dim3(256), 0, stream>>>(feat, wg1, bg1, wg2, bg2, fcw, fcb, out);
}